// Round 12
// baseline (75.339 us; speedup 1.0000x reference)
//
#include <hip/hip_runtime.h>
#include <math.h>

typedef _Float16 f16;
typedef _Float16 half4 __attribute__((ext_vector_type(4)));
typedef _Float16 half8 __attribute__((ext_vector_type(8)));
typedef float f32x4 __attribute__((ext_vector_type(4)));

#define NK 256
#define LW 249
#define WHS 256          // Wh row stride (f16, zero-padded)
#define TLEN 2000
#define PAD 124
#define NCOPY 8
#define CPL3 792         // elems/copy; 396 dwords == 12 mod 32 -> conflict-free b128
#define CPW3 768         // staged elems per copy (max read idx 767)
#define THREADS 512
#define NQ 4             // t-quarters

// ws layout (bytes)
#define WS_BIASP (NK * WHS * 2)
#define WS_PERM  (WS_BIASP + NK * 4)
#define WS_TM    (WS_PERM + NK * 4)
#define WS_MROW  (WS_TM + 64)
#define WS_WP    (WS_MROW + NK * 4)
#define WS_PART  (WS_WP + 64)          // float2 part[4][256][256] = 2 MB

// ---- prep 1: per-row tap extent -> window size M (one wave per row) ----
__global__ __launch_bounds__(64) void scan_extents(const float* __restrict__ W,
                                                   int* __restrict__ Mrow) {
  const int k = blockIdx.x, lane = threadIdx.x;
  int mn = 1 << 30, mx = -1;
  for (int l = lane; l < LW; l += 64) {
    if (W[k * LW + l] != 0.0f) { mn = min(mn, l); mx = max(mx, l); }
  }
#pragma unroll
  for (int s = 32; s; s >>= 1) {
    mn = min(mn, __shfl_xor(mn, s, 64));
    mx = max(mx, __shfl_xor(mx, s, 64));
  }
  if (lane == 0) {
    if (mx < 0) { mn = 124; mx = 124; }
    const int lo = mn >> 5, hi = (mx >> 5) + 1;
    int M = max(4 - lo, hi - 4);
    Mrow[k] = min(max(M, 1), 4);        // taps centered -> kb window [4-M, 4+M)
  }
}

// ---- prep 2: rank-sort by M; pair tiles (p,15-p); snake-assign pairs to waves ----
__global__ __launch_bounds__(256) void rank_rows(const int* __restrict__ Mrow,
                                                 const float* __restrict__ bias,
                                                 float* __restrict__ biasP,
                                                 int* __restrict__ perm,
                                                 int* __restrict__ tileM,
                                                 int* __restrict__ wavePair) {
  __shared__ int s_m[NK];
  __shared__ int s_perm[NK];
  __shared__ int s_tm[16];
  const int k = threadIdx.x;
  s_m[k] = Mrow[k];
  __syncthreads();
  const int M = s_m[k];
  int pos = 0;
  for (int j = 0; j < NK; ++j) {
    const int Mj = s_m[j];
    pos += (Mj < M || (Mj == M && j < k)) ? 1 : 0;   // stable rank
  }
  s_perm[pos] = k;
  __syncthreads();
  perm[k]  = s_perm[k];
  biasP[k] = bias[s_perm[k]];
  if (k < 16) {
    int mM = 1;
    for (int j = 0; j < 16; ++j) mM = max(mM, s_m[s_perm[k * 16 + j]]);
    s_tm[k] = mM;
    tileM[k] = mM;
  }
  __syncthreads();
  if (k == 0) {
    // pair p = tiles (p, 15-p); cost = M sum; sort pairs desc; snake to waves
    int c[8], pidx[8];
    for (int p = 0; p < 8; ++p) { c[p] = s_tm[p] + s_tm[15 - p]; pidx[p] = p; }
    for (int i = 1; i < 8; ++i) {        // insertion sort desc, stable
      int cv = c[i], pv = pidx[i], j = i - 1;
      while (j >= 0 && c[j] < cv) { c[j + 1] = c[j]; pidx[j + 1] = pidx[j]; --j; }
      c[j + 1] = cv; pidx[j + 1] = pv;
    }
    const int worder[8] = {0, 1, 2, 3, 7, 6, 5, 4};  // SIMD snake 0,1,2,3,3,2,1,0
    for (int i = 0; i < 8; ++i) wavePair[worder[i]] = pidx[i];
  }
}

// ---- prep 3: permuted f16 weights ----
__global__ __launch_bounds__(256) void permute_W(const float* __restrict__ W,
                                                 const int* __restrict__ perm,
                                                 f16* __restrict__ Wh) {
  const int r = blockIdx.x, l = threadIdx.x;
  const int src = perm[r];
  Wh[r * WHS + l] = (l < LW) ? (f16)W[src * LW + l] : (f16)0.0f;
}

// ---- per-wave templated loop over a t-QUARTER; ALL reg indices static (R10 loop) ----
template <int M>
__device__ __forceinline__ void run_tile(const f16* xc, const f16* __restrict__ Wh,
                                         const float* __restrict__ biasP,
                                         float2* __restrict__ part,
                                         int bc, int q, int tile, int l15, int lq,
                                         int cpyBase) {
  constexpr int KLO = 4 - M;
  half8 af[2 * M];
#pragma unroll
  for (int a = 0; a < 2 * M; ++a)
    af[a] = *(const half8*)&Wh[(tile * 16 + l15) * WHS + (KLO + a) * 32 + 8 * lq];

  float thr[4];
#pragma unroll
  for (int r = 0; r < 4; ++r) thr[r] = -biasP[tile * 16 + lq * 4 + r];

  const int nbase = q * 32;          // nt = nbase + p + 2u, u in [0,16)

  int cnt[4]; float mx[4];
#pragma unroll
  for (int r = 0; r < 4; ++r) { cnt[r] = 0; mx[r] = -INFINITY; }

  for (int p = 0; p < 2; ++p) {
    const int b0 = cpyBase + p * 16;  // physical; logical base 512q removed in staging
    half8 R[8];
#pragma unroll
    for (int kb = 0; kb < 8; ++kb) R[kb] = *(const half8*)&xc[b0 + kb * 32];

    for (int it = 0; it < 2; ++it) {
#pragma unroll
      for (int ui = 0; ui < 8; ++ui) {
        const int u  = it * 8 + ui;
        const int nt = nbase + p + 2 * u;
        f32x4 acc0 = (f32x4){0, 0, 0, 0}, acc1 = (f32x4){0, 0, 0, 0};
#pragma unroll
        for (int a = 0; a < 2 * M; ++a) {
          const int kb = KLO + a;                      // compile-time
          const half8 b = R[(ui + kb) & 7];            // static slot
          if (a & 1) acc1 = __builtin_amdgcn_mfma_f32_16x16x32_f16(af[a], b, acc1, 0, 0, 0);
          else       acc0 = __builtin_amdgcn_mfma_f32_16x16x32_f16(af[a], b, acc0, 0, 0, 0);
        }
        R[ui] = *(const half8*)&xc[b0 + 32 * u + 256]; // static slot slide (max idx 767)
        if (nt <= 124) {
#pragma unroll
          for (int r = 0; r < 4; ++r) {
            const float v = acc0[r] + acc1[r];
            cnt[r] += (v > thr[r]) ? 1 : 0;
            mx[r]   = fmaxf(mx[r], v);
          }
        }
      }
    }
  }

  // reduce over the 16 lanes sharing each k; write partial (sorted index space)
#pragma unroll
  for (int r = 0; r < 4; ++r) {
    float c0 = (float)cnt[r], m0 = mx[r];
#pragma unroll
    for (int s = 1; s < 16; s <<= 1) {
      c0 += __shfl_xor(c0, s, 16);
      m0  = fmaxf(m0, __shfl_xor(m0, s, 16));
    }
    if (l15 == 0) {
      const int ks = tile * 16 + lq * 4 + r;
      part[(q * NK + bc) * NK + ks] = make_float2(c0, m0);
    }
  }
}

__device__ __forceinline__ void dispatch_tile(const f16* xc, const f16* Wh,
                                              const float* biasP, float2* part,
                                              int bc, int q, int tile, int M,
                                              int l15, int lq, int cpyBase) {
  switch (M) {
    case 1:  run_tile<1>(xc, Wh, biasP, part, bc, q, tile, l15, lq, cpyBase); break;
    case 2:  run_tile<2>(xc, Wh, biasP, part, bc, q, tile, l15, lq, cpyBase); break;
    case 3:  run_tile<3>(xc, Wh, biasP, part, bc, q, tile, l15, lq, cpyBase); break;
    default: run_tile<4>(xc, Wh, biasP, part, bc, q, tile, l15, lq, cpyBase); break;
  }
}

__global__ __launch_bounds__(THREADS, 4) void rocket_mfma(
    const float* __restrict__ x, const f16* __restrict__ Wh,
    const float* __restrict__ biasP, const int* __restrict__ tileM,
    const int* __restrict__ wavePair, float2* __restrict__ part) {
  __shared__ f16 xc[NCOPY * CPL3];

  const int bc   = blockIdx.x;        // 0..255
  const int q    = blockIdx.y;        // 0..3 t-quarter
  const int tid  = threadIdx.x;
  const int wid  = tid >> 6;
  const int lane = tid & 63;
  const int l15  = lane & 15;
  const int lq   = lane >> 4;

  // stage 8 shifted f16 copies of this quarter's window:
  // xc[c][i] = xpad(i + 512q + c), xpad(j) = x[j - PAD]
  const float* xrow = x + bc * TLEN;
  const int gbase = q * 512 - PAD;
  for (int idx = tid * 4; idx < NCOPY * CPW3; idx += THREADS * 4) {
    const int cpy = idx / CPW3;
    const int i   = idx - cpy * CPW3;
    half4 v;
#pragma unroll
    for (int r = 0; r < 4; ++r) {
      const int g = gbase + i + r + cpy;
      v[r] = (g >= 0 && g < TLEN) ? (f16)xrow[g] : (f16)0.0f;
    }
    *(half4*)&xc[cpy * CPL3 + i] = v;
  }
  __syncthreads();

  // load-balanced pair for this wave, rotated across blocks so heavy pairs
  // visit different SIMDs on different CUs/blocks
  const int pr    = __builtin_amdgcn_readfirstlane(wavePair[(wid + bc) & 7]);
  const int tileA = pr, tileB = 15 - pr;
  const int MA    = __builtin_amdgcn_readfirstlane(tileM[tileA]);
  const int MB    = __builtin_amdgcn_readfirstlane(tileM[tileB]);

  const int lane_e  = 8 * lq + l15;
  const int cpy     = l15 & 7;
  const int cpyBase = cpy * CPL3 + (lane_e - cpy);

  dispatch_tile(xc, Wh, biasP, part, bc, q, tileA, MA, l15, lq, cpyBase);
  dispatch_tile(xc, Wh, biasP, part, bc, q, tileB, MB, l15, lq, cpyBase);
}

// ---- combine the four t-quarters, un-permute, finalize ----
__global__ __launch_bounds__(256) void combine(const float2* __restrict__ part,
                                               const float* __restrict__ biasP,
                                               const int* __restrict__ perm,
                                               float* __restrict__ out) {
  const int bc = blockIdx.x, ks = threadIdx.x;
  float cnt = 0.0f, mx = -INFINITY;
#pragma unroll
  for (int q = 0; q < NQ; ++q) {
    const float2 pq = part[(q * NK + bc) * NK + ks];
    cnt += pq.x;
    mx = fmaxf(mx, pq.y);
  }
  const int ko = perm[ks];
  float2 res;
  res.x = cnt * (1.0f / (float)TLEN);
  res.y = mx + biasP[ks];
  *(float2*)&out[bc * (2 * NK) + 2 * ko] = res;
}

extern "C" void kernel_launch(void* const* d_in, const int* in_sizes, int n_in,
                              void* d_out, int out_size, void* d_ws, size_t ws_size,
                              hipStream_t stream) {
  const float* x    = (const float*)d_in[0];   // (8,32,2000)
  const float* W    = (const float*)d_in[1];   // (256,249)
  const float* bias = (const float*)d_in[2];   // (256,)
  float* out = (float*)d_out;                  // (8,32,512)

  f16*    Wh    = (f16*)d_ws;
  float*  biasP = (float*)((char*)d_ws + WS_BIASP);
  int*    perm  = (int*)((char*)d_ws + WS_PERM);
  int*    tileM = (int*)((char*)d_ws + WS_TM);
  int*    Mrow  = (int*)((char*)d_ws + WS_MROW);
  int*    wPair = (int*)((char*)d_ws + WS_WP);
  float2* partP = (float2*)((char*)d_ws + WS_PART);

  scan_extents<<<NK, 64, 0, stream>>>(W, Mrow);
  rank_rows<<<1, 256, 0, stream>>>(Mrow, bias, biasP, perm, tileM, wPair);
  permute_W<<<NK, 256, 0, stream>>>(W, perm, Wh);
  rocket_mfma<<<dim3(NK, NQ), THREADS, 0, stream>>>(x, Wh, biasP, tileM, wPair, partP);
  combine<<<NK, 256, 0, stream>>>(partP, biasP, perm, out);
}